// Round 14
// baseline (93.805 us; speedup 1.0000x reference)
//
#include <hip/hip_runtime.h>

#define BD 64
#define SD 512
#define DD 1024
#define HD 1024
#define TD 9
#define NSEG 32
#define SEGL 16
#define NEGI -1e30f

__device__ __forceinline__ float lse9(const float v[9]) {
    float m0 = fmaxf(v[0], v[1]);
    float m1 = fmaxf(v[2], v[3]);
    float m2 = fmaxf(v[4], v[5]);
    float m3 = fmaxf(v[6], v[7]);
    float mx = fmaxf(fmaxf(m0, m1), fmaxf(fmaxf(m2, m3), v[8]));
    float s = __expf(v[0] - mx) + __expf(v[1] - mx) + __expf(v[2] - mx)
            + __expf(v[3] - mx) + __expf(v[4] - mx) + __expf(v[5] - mx)
            + __expf(v[6] - mx) + __expf(v[7] - mx) + __expf(v[8] - mx);
    return mx + __logf(s);
}

// ---------------- Kernel A: W12t[t][d] (+ transposed W12d[d][t]); b12 ----------------
__global__ __launch_bounds__(256) void k_w12(const float* __restrict__ W1,
                                             const float* __restrict__ b1,
                                             const float* __restrict__ W2,
                                             const float* __restrict__ b2,
                                             float* __restrict__ W12t,
                                             float* __restrict__ W12d,
                                             float* __restrict__ b12,
                                             float* __restrict__ out) {
    __shared__ float wred[4][TD];
    const int tid = threadIdx.x;
    const int wave = tid >> 6, lane = tid & 63;
    const int d = blockIdx.x;

    if (d == 0 && tid == 0) out[0] = 0.f;

    const float* row = (d < DD) ? (W1 + (size_t)d * HD) : b1;
    float4 x = ((const float4*)row)[tid];   // h = tid*4 .. tid*4+3

    float w[36];                             // W2[tid*4+u][t]
    const float4* wp = (const float4*)(W2 + (size_t)tid * 36);
#pragma unroll
    for (int u = 0; u < 9; u++) ((float4*)w)[u] = wp[u];

    float acc[TD];
#pragma unroll
    for (int t = 0; t < TD; t++)
        acc[t] = x.x * w[t] + x.y * w[9 + t] + x.z * w[18 + t] + x.w * w[27 + t];

#pragma unroll
    for (int t = 0; t < TD; t++) {
        float v = acc[t];
#pragma unroll
        for (int m = 1; m < 64; m <<= 1) v += __shfl_xor(v, m);
        acc[t] = v;
    }
    if (lane == 0) {
#pragma unroll
        for (int t = 0; t < TD; t++) wred[wave][t] = acc[t];
    }
    __syncthreads();
    if (tid < TD) {
        float s = wred[0][tid] + wred[1][tid] + wred[2][tid] + wred[3][tid];
        if (d < DD) {
            W12t[tid * DD + d] = s;
            W12d[d * TD + tid] = s;
        } else {
            b12[tid] = s + b2[tid];
        }
    }
}

// ---------------- Kernel B: fused logits GEMM + 16-leaf semiring tree ----------------
// Grid 2048 = (b, s): b = blk>>5, s = blk&31. 16 groups x 16 lanes x 1 row = rows
// t0+1..t0+16 = the 16 leaves. Global weight reads (L1/L2-resident). ~5 KB LDS,
// ~50 VGPR -> 8 blocks/CU, 32 waves/CU (max occupancy).
__global__ __launch_bounds__(256) void k_gemm_seg(const float* __restrict__ X,
                                                  const float* __restrict__ W12t,
                                                  const float* __restrict__ b12,
                                                  const int* __restrict__ maskp,
                                                  const float* __restrict__ transp,
                                                  float* __restrict__ logits,
                                                  float* __restrict__ segP) {
    __shared__ float bufA[8 * 81];      // 648
    __shared__ float bufB[4 * 81];      // 324
    __shared__ float em[SEGL * TD];     // 144
    __shared__ int   mk[SEGL];
    __shared__ float tr[81];
    __shared__ float bb[TD];

    const int blk = blockIdx.x;
    const int b = blk >> 5, s = blk & 31;
    const int tid = threadIdx.x;
    const int wave = tid >> 6, lane = tid & 63;
    const int g = lane >> 4, l16 = lane & 15;
    const int grp = wave * 4 + g;        // 0..15, one row each
    const int t0 = s * SEGL;

    if (tid < TD) bb[tid] = b12[tid];
    if (tid < 81) tr[tid] = transp[tid];
    if (tid < SEGL) {
        int t = t0 + 1 + tid;
        mk[tid] = (t < SD) ? maskp[b * SD + t] : 0;
    }
    __syncthreads();

    // ---- GEMM phase: row t0+1+grp (leaf = grp) ----
    const int rowa = t0 + 1 + grp;
    const int rowc = (rowa < SD) ? rowa : (SD - 1);  // clamp only s=31,grp=15
    const float4* xr = (const float4*)(X + ((size_t)b * SD + rowc) * DD);

    const float4* wr[TD];
#pragma unroll
    for (int t = 0; t < TD; t++)
        wr[t] = (const float4*)(W12t + (size_t)t * DD) + l16;

    float acc[TD];
#pragma unroll
    for (int t = 0; t < TD; t++) acc[t] = 0.f;

#pragma unroll 4
    for (int k = 0; k < 16; k++) {
        float4 x0 = xr[l16 + k * 16];
#pragma unroll
        for (int t = 0; t < TD; t++) {
            const float4 w = wr[t][k * 16];
            acc[t] += x0.x * w.x + x0.y * w.y + x0.z * w.z + x0.w * w.w;
        }
    }

#pragma unroll
    for (int t = 0; t < TD; t++) {
        float v = acc[t];
        v += __shfl_xor(v, 1);
        v += __shfl_xor(v, 2);
        v += __shfl_xor(v, 4);
        v += __shfl_xor(v, 8);
        acc[t] = v;
    }

    if (l16 < TD) {
        float v0 = acc[l16] + bb[l16];
        em[grp * TD + l16] = v0;                // junk if masked leaf; never read
        if (rowa < SD) {
            float* o = logits + ((size_t)b * SD + rowa) * TD;
            o[l16] = v0;
        }
    }
    __syncthreads();

    // ---- tree phase: 16 leaves -> 8 -> 4 -> 2 -> 1 ----
    for (int e = tid; e < 8 * 81; e += 256) {
        int p = e / 81, r = e - p * 81;
        int i = r / 9, j = r - i * 9;
        int la = 2 * p, lb = 2 * p + 1;
        int mA = mk[la], mB = mk[lb];
        float o;
        if (mA && mB) {
            float v[9];
#pragma unroll
            for (int k = 0; k < 9; k++)
                v[k] = tr[i * 9 + k] + em[la * 9 + k] + tr[k * 9 + j];
            o = lse9(v) + em[lb * 9 + j];
        } else if (mA) {
            o = tr[r] + em[la * 9 + j];
        } else if (mB) {
            o = tr[r] + em[lb * 9 + j];
        } else {
            o = (i == j) ? 0.f : NEGI;
        }
        bufA[e] = o;
    }
    __syncthreads();

#define COMBINE(SRC, DST, NP)                                        \
    for (int e = tid; e < (NP) * 81; e += 256) {                     \
        int p = e / 81, r = e - p * 81;                              \
        int i = r / 9, j = r - i * 9;                                \
        const float* Am = (SRC) + (2 * p) * 81;                      \
        const float* Bm = Am + 81;                                   \
        float v[9];                                                  \
        _Pragma("unroll")                                            \
        for (int k = 0; k < 9; k++) v[k] = Am[i * 9 + k] + Bm[k * 9 + j]; \
        (DST)[e] = lse9(v);                                          \
    }                                                                \
    __syncthreads();

    COMBINE(bufA, bufB, 4)    // 8 -> 4
    COMBINE(bufB, bufA, 2)    // 4 -> 2

    if (tid < 81) {           // 2 -> 1, straight to global
        int i = tid / 9, j = tid - (tid / 9) * 9;
        float v[9];
#pragma unroll
        for (int k = 0; k < 9; k++) v[k] = bufA[i * 9 + k] + bufA[81 + k * 9 + j];
        segP[(size_t)blk * 81 + tid] = lse9(v);
    }
}

// ---------------- Kernel C: row-0 logits + combine 32 seg matrices + loss ----------------
__global__ __launch_bounds__(256) void k_crf_fin(const float* __restrict__ X,
                                                 const float* __restrict__ W12d,
                                                 const float* __restrict__ b12,
                                                 const float* __restrict__ logits,
                                                 const int* __restrict__ labels,
                                                 const int* __restrict__ maskp,
                                                 const float* __restrict__ startp,
                                                 const float* __restrict__ endp,
                                                 const float* __restrict__ transp,
                                                 const float* __restrict__ segP,
                                                 float* __restrict__ logits_out0,
                                                 float* __restrict__ out) {
    const int b = blockIdx.x;
    const int tid = threadIdx.x;
    const int wave = tid >> 6, lane = tid & 63;

    __shared__ float S[32 * 81];     // 2592
    __shared__ float A16[16 * 81];   // 1296
    __shared__ float A8[8 * 81];
    __shared__ float A4[4 * 81];
    __shared__ float A2[2 * 81];
    __shared__ float P[81];
    __shared__ float finv[81];
    __shared__ float red[256];
    __shared__ int   redi[256];
    __shared__ float wred[4][TD];
    __shared__ float row0[TD];

    // ---- logits row 0 for batch b ----
    {
        float4 x = ((const float4*)(X + (size_t)b * SD * DD))[tid];
        float w[36];
        const float4* wp = (const float4*)(W12d + (size_t)tid * 36);
#pragma unroll
        for (int u = 0; u < 9; u++) ((float4*)w)[u] = wp[u];
        float acc[TD];
#pragma unroll
        for (int t = 0; t < TD; t++)
            acc[t] = x.x * w[t] + x.y * w[9 + t] + x.z * w[18 + t] + x.w * w[27 + t];
#pragma unroll
        for (int t = 0; t < TD; t++) {
            float v = acc[t];
#pragma unroll
            for (int m = 1; m < 64; m <<= 1) v += __shfl_xor(v, m);
            acc[t] = v;
        }
        if (lane == 0) {
#pragma unroll
            for (int t = 0; t < TD; t++) wred[wave][t] = acc[t];
        }
    }

    for (int i = tid; i < 32 * 81; i += 256) S[i] = segP[(size_t)b * NSEG * 81 + i];
    __syncthreads();

    if (tid < TD) {
        float v = wred[0][tid] + wred[1][tid] + wred[2][tid] + wred[3][tid] + b12[tid];
        row0[tid] = v;
        logits_out0[(size_t)b * SD * TD + tid] = v;
    }

    COMBINE(S, A16, 16)   // 32 -> 16
    COMBINE(A16, A8, 8)   // 16 -> 8
    COMBINE(A8, A4, 4)    // 8  -> 4
    COMBINE(A4, A2, 2)    // 4  -> 2

    if (tid < 81) {
        int i = tid / 9, j = tid - (tid / 9) * 9;
        float v[9];
#pragma unroll
        for (int k = 0; k < 9; k++) v[k] = A2[i * 9 + k] + A2[81 + k * 9 + j];
        P[tid] = lse9(v);
    }
    __syncthreads();

    if (tid < 81) {
        int k = tid / 9, j = tid - (tid / 9) * 9;
        finv[tid] = startp[k] + row0[k] + P[tid] + endp[j];
    }

    float part = 0.f;
    for (int t = 1 + tid; t < SD; t += 256) {
        if (maskp[b * SD + t]) {
            int tgp = labels[b * SD + t - 1];
            int tgc = labels[b * SD + t];
            part += transp[tgp * TD + tgc] + logits[((size_t)b * SD + t) * TD + tgc];
        }
    }
    int lastt = 0;
    for (int t = tid; t < SD; t += 256) {
        if (maskp[b * SD + t]) lastt = max(lastt, t);
    }
    red[tid] = part;
    redi[tid] = lastt;
    __syncthreads();

    if (tid < 64) {
        float p4 = red[tid] + red[tid + 64] + red[tid + 128] + red[tid + 192];
        int l4 = max(max(redi[tid], redi[tid + 64]), max(redi[tid + 128], redi[tid + 192]));
#pragma unroll
        for (int m = 1; m < 64; m <<= 1) {
            p4 += __shfl_xor(p4, m);
            l4 = max(l4, __shfl_xor(l4, m));
        }
        float v1 = finv[tid];
        float v2 = (tid + 64 < 81) ? finv[tid + 64] : NEGI;
        float mx = fmaxf(v1, v2);
#pragma unroll
        for (int m = 1; m < 64; m <<= 1) mx = fmaxf(mx, __shfl_xor(mx, m));
        float ssum = __expf(v1 - mx) + __expf(v2 - mx);
#pragma unroll
        for (int m = 1; m < 64; m <<= 1) ssum += __shfl_xor(ssum, m);
        float logz = mx + __logf(ssum);

        if (tid == 0) {
            int tg0 = labels[b * SD];
            int tgl = labels[b * SD + l4];
            float score = p4 + startp[tg0] + row0[tg0] + endp[tgl];
            atomicAdd(out, -(score - logz) / (float)BD);   // out zeroed by k_w12
        }
    }
}

extern "C" void kernel_launch(void* const* d_in, const int* in_sizes, int n_in,
                              void* d_out, int out_size, void* d_ws, size_t ws_size,
                              hipStream_t stream) {
    const float* X      = (const float*)d_in[0];
    const int*   labels = (const int*)d_in[1];
    const int*   maskp  = (const int*)d_in[2];
    const float* W1     = (const float*)d_in[3];
    const float* b1     = (const float*)d_in[4];
    const float* W2     = (const float*)d_in[5];
    const float* b2     = (const float*)d_in[6];
    const float* startp = (const float*)d_in[7];
    const float* endp   = (const float*)d_in[8];
    const float* transp = (const float*)d_in[9];

    float* out = (float*)d_out;
    float* ws = (float*)d_ws;

    float* W12t = ws + 64;                          // 9216 floats
    float* b12  = ws + 64 + DD * TD;                // 9 (+pad)
    float* segP = ws + 64 + DD * TD + 16;           // 64*32*81 = 165888 floats
    float* W12d = segP + (size_t)BD * NSEG * 81;    // 9216 floats
    float* logits = out + 1;                        // [B,S,T] fp32

    hipLaunchKernelGGL(k_w12, dim3(DD + 1), dim3(256), 0, stream,
                       W1, b1, W2, b2, W12t, W12d, b12, out);
    hipLaunchKernelGGL(k_gemm_seg, dim3(BD * NSEG), dim3(256), 0, stream,
                       X, W12t, b12, maskp, transp, logits, segP);
    hipLaunchKernelGGL(k_crf_fin, dim3(BD), dim3(256), 0, stream,
                       X, W12d, b12, logits, labels, maskp, startp, endp, transp,
                       segP, logits, out);
}

// Round 15
// 60.871 us; speedup vs baseline: 1.5410x; 1.5410x over previous
//
#include <hip/hip_runtime.h>

#define BD 64
#define SD 512
#define DD 1024
#define HD 1024
#define TD 9
#define NSEG 16
#define SEGL 32
#define HK 128          // float4s per half-row (512 floats)
#define NEGI -1e30f

__device__ __forceinline__ float lse9(const float v[9]) {
    float m0 = fmaxf(v[0], v[1]);
    float m1 = fmaxf(v[2], v[3]);
    float m2 = fmaxf(v[4], v[5]);
    float m3 = fmaxf(v[6], v[7]);
    float mx = fmaxf(fmaxf(m0, m1), fmaxf(fmaxf(m2, m3), v[8]));
    float s = __expf(v[0] - mx) + __expf(v[1] - mx) + __expf(v[2] - mx)
            + __expf(v[3] - mx) + __expf(v[4] - mx) + __expf(v[5] - mx)
            + __expf(v[6] - mx) + __expf(v[7] - mx) + __expf(v[8] - mx);
    return mx + __logf(s);
}

// ---------------- Kernel A: W12t[t][d]; b12; zero logits & out[0] ----------------
// 1025 blocks, register-resident W2 slice. Each block also zeroes its 288-float
// slice of logits (accumulated by atomicAdd in k_gemm2h this same call).
__global__ __launch_bounds__(256) void k_w12(const float* __restrict__ W1,
                                             const float* __restrict__ b1,
                                             const float* __restrict__ W2,
                                             const float* __restrict__ b2,
                                             float* __restrict__ W12t,
                                             float* __restrict__ b12,
                                             float* __restrict__ logits,
                                             float* __restrict__ out) {
    __shared__ float wred[4][TD];
    const int tid = threadIdx.x;
    const int wave = tid >> 6, lane = tid & 63;
    const int d = blockIdx.x;

    if (d == 0 && tid == 0) out[0] = 0.f;
    {   // zero logits slice: 1025 blocks x 288 covers 294912 floats
        int base = d * 288;
        for (int i = tid; i < 288; i += 256) {
            int idx = base + i;
            if (idx < BD * SD * TD) logits[idx] = 0.f;
        }
    }

    const float* row = (d < DD) ? (W1 + (size_t)d * HD) : b1;
    float4 x = ((const float4*)row)[tid];   // h = tid*4 .. tid*4+3

    float w[36];                             // W2[tid*4+u][t]
    const float4* wp = (const float4*)(W2 + (size_t)tid * 36);
#pragma unroll
    for (int u = 0; u < 9; u++) ((float4*)w)[u] = wp[u];

    float acc[TD];
#pragma unroll
    for (int t = 0; t < TD; t++)
        acc[t] = x.x * w[t] + x.y * w[9 + t] + x.z * w[18 + t] + x.w * w[27 + t];

#pragma unroll
    for (int t = 0; t < TD; t++) {
        float v = acc[t];
#pragma unroll
        for (int m = 1; m < 64; m <<= 1) v += __shfl_xor(v, m);
        acc[t] = v;
    }
    if (lane == 0) {
#pragma unroll
        for (int t = 0; t < TD; t++) wred[wave][t] = acc[t];
    }
    __syncthreads();
    if (tid < TD) {
        float s = wred[0][tid] + wred[1][tid] + wred[2][tid] + wred[3][tid];
        if (d < DD) W12t[tid * DD + d] = s;
        else        b12[tid] = s + b2[tid];
    }
}

// ---------------- Kernel B: half-D GEMM, atomicAdd combine ----------------
// Grid 2048 = (rowgrp 0..1023) x (half 0..1). 18 KiB LDS half-tile -> 8 blocks/CU,
// 32 waves/CU. Same per-thread register shape as the proven R=2 16-lane kernel.
// logits zeroed upstream; two commutative fp32 atomicAdds -> deterministic result.
__global__ __launch_bounds__(256) void k_gemm2h(const float* __restrict__ X,
                                                const float* __restrict__ W12t,
                                                const float* __restrict__ b12,
                                                float* __restrict__ logits) {
    __shared__ float wt[TD][HK * 4];    // 18 KiB
    __shared__ float bb[TD];

    const int blk = blockIdx.x;
    const int h = blk & 1, rowgrp = blk >> 1;
    const int tid = threadIdx.x;

    for (int i = tid; i < TD * HK; i += 256) {
        int t = i >> 7, d4 = i & (HK - 1);
        ((float4*)&wt[t][0])[d4] = ((const float4*)W12t)[t * 256 + h * HK + d4];
    }
    if (tid < TD) bb[tid] = b12[tid];
    __syncthreads();

    const int wave = tid >> 6, lane = tid & 63;
    const int g = lane >> 4, l16 = lane & 15;
    const int row0 = rowgrp * 32 + wave * 8 + g * 2;

    const float4* xr0 = (const float4*)(X + (size_t)row0 * DD) + h * HK;
    const float4* xr1 = xr0 + DD / 4;

    float acc0[TD], acc1[TD];
#pragma unroll
    for (int t = 0; t < TD; t++) { acc0[t] = 0.f; acc1[t] = 0.f; }

#pragma unroll 4
    for (int k = 0; k < 8; k++) {
        int d4 = l16 + k * 16;
        float4 x0 = xr0[d4];
        float4 x1 = xr1[d4];
#pragma unroll
        for (int t = 0; t < TD; t++) {
            const float4 w = *(const float4*)&wt[t][d4 * 4];
            acc0[t] += x0.x * w.x + x0.y * w.y + x0.z * w.z + x0.w * w.w;
            acc1[t] += x1.x * w.x + x1.y * w.y + x1.z * w.z + x1.w * w.w;
        }
    }

#pragma unroll
    for (int t = 0; t < TD; t++) {
        float v0 = acc0[t], v1 = acc1[t];
        v0 += __shfl_xor(v0, 1); v1 += __shfl_xor(v1, 1);
        v0 += __shfl_xor(v0, 2); v1 += __shfl_xor(v1, 2);
        v0 += __shfl_xor(v0, 4); v1 += __shfl_xor(v1, 4);
        v0 += __shfl_xor(v0, 8); v1 += __shfl_xor(v1, 8);
        acc0[t] = v0; acc1[t] = v1;
    }

    if (l16 < TD) {
        float a0 = acc0[l16] + (h ? 0.f : bb[l16]);
        float a1 = acc1[l16] + (h ? 0.f : bb[l16]);
        float* o = logits + (size_t)row0 * TD;
        atomicAdd(&o[l16], a0);
        atomicAdd(&o[TD + l16], a1);
    }
}

// ---------------- Kernel C1: 32-leaf per-segment semiring tree (R8-proven) ----------------
__global__ __launch_bounds__(256) void k_crf_seg(const float* __restrict__ logits,
                                                 const int* __restrict__ maskp,
                                                 const float* __restrict__ transp,
                                                 float* __restrict__ segP) {
    const int blk = blockIdx.x;
    const int b = blk >> 4, s = blk & 15;
    const int tid = threadIdx.x;

    __shared__ float tr[81];
    __shared__ float em[SEGL * 9];
    __shared__ int   mk[SEGL];
    __shared__ float bufA[16 * 81];
    __shared__ float bufB[8 * 81];

    const int t0 = s * SEGL + 1;

    {
        const float* src = logits + ((size_t)b * SD + t0) * TD;
        for (int i = tid; i < SEGL * 9; i += 256)
            em[i] = (t0 + i / 9 < SD) ? src[i] : 0.f;
    }
    if (tid < SEGL) {
        int t = t0 + tid;
        mk[tid] = (t < SD) ? maskp[b * SD + t] : 0;
    }
    if (tid < 81) tr[tid] = transp[tid];
    __syncthreads();

    for (int e = tid; e < 16 * 81; e += 256) {
        int p = e / 81, r = e - p * 81;
        int i = r / 9, j = r - i * 9;
        int la = 2 * p, lb = 2 * p + 1;
        int mA = mk[la], mB = mk[lb];
        float o;
        if (mA && mB) {
            float v[9];
#pragma unroll
            for (int k = 0; k < 9; k++)
                v[k] = tr[i * 9 + k] + em[la * 9 + k] + tr[k * 9 + j];
            o = lse9(v) + em[lb * 9 + j];
        } else if (mA) {
            o = tr[r] + em[la * 9 + j];
        } else if (mB) {
            o = tr[r] + em[lb * 9 + j];
        } else {
            o = (i == j) ? 0.f : NEGI;
        }
        bufA[e] = o;
    }
    __syncthreads();

#define COMBINE(SRC, DST, NP)                                        \
    for (int e = tid; e < (NP) * 81; e += 256) {                     \
        int p = e / 81, r = e - p * 81;                              \
        int i = r / 9, j = r - i * 9;                                \
        const float* Am = (SRC) + (2 * p) * 81;                      \
        const float* Bm = Am + 81;                                   \
        float v[9];                                                  \
        _Pragma("unroll")                                            \
        for (int k = 0; k < 9; k++) v[k] = Am[i * 9 + k] + Bm[k * 9 + j]; \
        (DST)[e] = lse9(v);                                          \
    }                                                                \
    __syncthreads();

    COMBINE(bufA, bufB, 8)    // 16 -> 8
    COMBINE(bufB, bufA, 4)    // 8  -> 4
    COMBINE(bufA, bufB, 2)    // 4  -> 2

    if (tid < 81) {
        int i = tid / 9, j = tid - (tid / 9) * 9;
        float v[9];
#pragma unroll
        for (int k = 0; k < 9; k++) v[k] = bufB[i * 9 + k] + bufB[81 + k * 9 + j];
        segP[(size_t)blk * 81 + tid] = lse9(v);
    }
}

// ---------------- Kernel C2: combine 16 seg matrices, log_z, numerator, loss ----------------
__global__ __launch_bounds__(256) void k_crf_fin(const float* __restrict__ logits,
                                                 const int* __restrict__ labels,
                                                 const int* __restrict__ maskp,
                                                 const float* __restrict__ startp,
                                                 const float* __restrict__ endp,
                                                 const float* __restrict__ transp,
                                                 const float* __restrict__ segP,
                                                 float* __restrict__ out) {
    const int b = blockIdx.x;
    const int tid = threadIdx.x;

    __shared__ float S[16 * 81];
    __shared__ float A8[8 * 81];
    __shared__ float A4[4 * 81];
    __shared__ float A2[2 * 81];
    __shared__ float P[81];
    __shared__ float finv[81];
    __shared__ float red[256];
    __shared__ int   redi[256];

    for (int i = tid; i < 16 * 81; i += 256) S[i] = segP[(size_t)b * NSEG * 81 + i];
    __syncthreads();

    COMBINE(S, A8, 8)     // 16 -> 8
    COMBINE(A8, A4, 4)    // 8  -> 4
    COMBINE(A4, A2, 2)    // 4  -> 2

    if (tid < 81) {
        int i = tid / 9, j = tid - (tid / 9) * 9;
        float v[9];
#pragma unroll
        for (int k = 0; k < 9; k++) v[k] = A2[i * 9 + k] + A2[81 + k * 9 + j];
        P[tid] = lse9(v);
    }
    __syncthreads();

    if (tid < 81) {
        int k = tid / 9, j = tid - (tid / 9) * 9;
        finv[tid] = startp[k] + logits[(size_t)b * SD * TD + k] + P[tid] + endp[j];
    }

    float part = 0.f;
    for (int t = 1 + tid; t < SD; t += 256) {
        if (maskp[b * SD + t]) {
            int tgp = labels[b * SD + t - 1];
            int tgc = labels[b * SD + t];
            part += transp[tgp * TD + tgc] + logits[((size_t)b * SD + t) * TD + tgc];
        }
    }
    int lastt = 0;
    for (int t = tid; t < SD; t += 256) {
        if (maskp[b * SD + t]) lastt = max(lastt, t);
    }
    red[tid] = part;
    redi[tid] = lastt;
    __syncthreads();

    if (tid < 64) {
        float p4 = red[tid] + red[tid + 64] + red[tid + 128] + red[tid + 192];
        int l4 = max(max(redi[tid], redi[tid + 64]), max(redi[tid + 128], redi[tid + 192]));
#pragma unroll
        for (int m = 1; m < 64; m <<= 1) {
            p4 += __shfl_xor(p4, m);
            l4 = max(l4, __shfl_xor(l4, m));
        }
        float v1 = finv[tid];
        float v2 = (tid + 64 < 81) ? finv[tid + 64] : NEGI;
        float mx = fmaxf(v1, v2);
#pragma unroll
        for (int m = 1; m < 64; m <<= 1) mx = fmaxf(mx, __shfl_xor(mx, m));
        float ssum = __expf(v1 - mx) + __expf(v2 - mx);
#pragma unroll
        for (int m = 1; m < 64; m <<= 1) ssum += __shfl_xor(ssum, m);
        float logz = mx + __logf(ssum);

        if (tid == 0) {
            int tg0 = labels[b * SD];
            int tgl = labels[b * SD + l4];
            float score = p4 + startp[tg0] + logits[(size_t)b * SD * TD + tg0] + endp[tgl];
            atomicAdd(out, -(score - logz) / (float)BD);   // out zeroed by k_w12
        }
    }
}

extern "C" void kernel_launch(void* const* d_in, const int* in_sizes, int n_in,
                              void* d_out, int out_size, void* d_ws, size_t ws_size,
                              hipStream_t stream) {
    const float* X      = (const float*)d_in[0];
    const int*   labels = (const int*)d_in[1];
    const int*   maskp  = (const int*)d_in[2];
    const float* W1     = (const float*)d_in[3];
    const float* b1     = (const float*)d_in[4];
    const float* W2     = (const float*)d_in[5];
    const float* b2     = (const float*)d_in[6];
    const float* startp = (const float*)d_in[7];
    const float* endp   = (const float*)d_in[8];
    const float* transp = (const float*)d_in[9];

    float* out = (float*)d_out;
    float* ws = (float*)d_ws;

    float* W12t = ws + 64;                  // 9216 floats
    float* b12  = ws + 64 + DD * TD;        // 9 (+pad)
    float* segP = ws + 64 + DD * TD + 16;   // 64*16*81 floats
    float* logits = out + 1;                // [B,S,T] fp32

    hipLaunchKernelGGL(k_w12, dim3(DD + 1), dim3(256), 0, stream,
                       W1, b1, W2, b2, W12t, b12, logits, out);
    hipLaunchKernelGGL(k_gemm2h, dim3(BD * SD / 32 * 2), dim3(256), 0, stream,
                       X, W12t, b12, logits);
    hipLaunchKernelGGL(k_crf_seg, dim3(BD * NSEG), dim3(256), 0, stream,
                       logits, maskp, transp, segP);
    hipLaunchKernelGGL(k_crf_fin, dim3(BD), dim3(256), 0, stream,
                       logits, labels, maskp, startp, endp, transp, segP, out);
}